// Round 1
// 1113.139 us; speedup vs baseline: 1.2028x; 1.2028x over previous
//
#include <hip/hip_runtime.h>

#define F 32
#define BN_EPS 1e-5f
#define SCAN_CHUNK 2048
#define BSH 11
#define BDST (1 << BSH)   // dsts per bucket
#define TILEE 8192        // edges per partition block

// All float tensors fp32 (verified R2 counters); indices int32.

// ---------------- weight prep ----------------
__global__ void prep_k(const float* __restrict__ th_mw, const float* __restrict__ th_mb,
                       const float* __restrict__ th_lw, const float* __restrict__ th_lb,
                       const float* __restrict__ ga_mw, const float* __restrict__ ga_mb,
                       const float* __restrict__ ga_lw, const float* __restrict__ ga_lb,
                       float* __restrict__ Wp) {
    int gs = gridDim.x * blockDim.x;
    int g0 = blockIdx.x * blockDim.x + threadIdx.x;
    float* WintX = Wp;
    float* WlX   = Wp + 4096;
    float* btX   = Wp + 7168;
    float* WintY = Wp + 7200;
    float* WlY   = Wp + 11296;
    float* btY   = Wp + 14368;
    for (int j = g0; j < 1024; j += gs) {
        int k = j >> 5, f = j & 31;
        for (int m = 0; m < 3; m++) {
            WintX[j * 4 + m] = th_mw[m * 1024 + f * 32 + k];
            WintY[j * 4 + m] = ga_mw[m * 1024 + f * 32 + k];
        }
        WintX[j * 4 + 3] = 0.f;
        WintY[j * 4 + 3] = 0.f;
    }
    for (int j = g0; j < 3072; j += gs) {
        int i = j >> 10, k = (j >> 5) & 31, f = j & 31;
        WlX[j] = th_lw[i * 1024 + f * 32 + k];
        WlY[j] = ga_lw[i * 1024 + f * 32 + k];
    }
    for (int f = g0; f < 32; f += gs) {
        float bx = 0.f, by = 0.f;
        for (int m = 0; m < 3; m++) {
            bx += th_mb[m * 32 + f] + th_lb[m * 32 + f];
            by += ga_mb[m * 32 + f] + ga_lb[m * 32 + f];
        }
        btX[f] = bx;
        btY[f] = by;
    }
}

// ---------------- g-graph CSR build (small, keep atomic path) ----------------
__global__ __launch_bounds__(256) void hist_k(const int* __restrict__ dst, int ne,
                                              int* __restrict__ counts) {
    int i = blockIdx.x * 256 + threadIdx.x;
    if (i < ne) atomicAdd(&counts[dst[i]], 1);
}

__global__ __launch_bounds__(256) void scan_block_k(const int* __restrict__ counts, int n,
                                                    int* __restrict__ rowptr,
                                                    int* __restrict__ bsums) {
    __shared__ int s[256];
    int tid = threadIdx.x;
    int b0 = blockIdx.x * SCAN_CHUNK;
    int v[8], tsum = 0;
#pragma unroll
    for (int j = 0; j < 8; j++) {
        int idx = b0 + tid * 8 + j;
        v[j] = (idx < n) ? counts[idx] : 0;
        tsum += v[j];
    }
    s[tid] = tsum;
    __syncthreads();
    for (int off = 1; off < 256; off <<= 1) {
        int t = (tid >= off) ? s[tid - off] : 0;
        __syncthreads();
        s[tid] += t;
        __syncthreads();
    }
    int run = s[tid] - tsum;
#pragma unroll
    for (int j = 0; j < 8; j++) {
        int idx = b0 + tid * 8 + j;
        if (idx < n) rowptr[idx] = run;
        run += v[j];
    }
    if (tid == 255) bsums[blockIdx.x] = s[255];
}

__global__ void scan_bsums_k(int* __restrict__ bsums, int nb) {
    __shared__ int s[256];
    int tid = threadIdx.x;
    int v = (tid < nb) ? bsums[tid] : 0;
    s[tid] = v;
    __syncthreads();
    for (int off = 1; off < 256; off <<= 1) {
        int t = (tid >= off) ? s[tid - off] : 0;
        __syncthreads();
        s[tid] += t;
        __syncthreads();
    }
    if (tid < nb) bsums[tid] = s[tid] - v;
}

__global__ __launch_bounds__(256) void scan_add_k(int* __restrict__ rowptr, int n, int ne,
                                                  const int* __restrict__ bsums) {
    int i = blockIdx.x * 256 + threadIdx.x;
    if (i < n) rowptr[i] += bsums[i / SCAN_CHUNK];
    if (i == 0) rowptr[n] = ne;
}

__global__ __launch_bounds__(256) void scatter_g_k(const int* __restrict__ src,
                                                   const int* __restrict__ dst, int ne,
                                                   int* __restrict__ cursor,
                                                   int* __restrict__ cs, int* __restrict__ ce) {
    int i = blockIdx.x * 256 + threadIdx.x;
    if (i >= ne) return;
    int p = atomicAdd(&cursor[dst[i]], 1);
    cs[p] = src[i];
    ce[p] = i;
}

// ---------------- lg CSR build: partitioned, write-amplification-free ----------------
__global__ __launch_bounds__(256) void bucket_hist_k(const int* __restrict__ dst, int ne,
                                                     int* __restrict__ bcnt, int nbuk) {
    __shared__ int h[1024];
    for (int i = threadIdx.x; i < nbuk; i += 256) h[i] = 0;
    __syncthreads();
    for (int i = blockIdx.x * 256 + threadIdx.x; i < ne; i += gridDim.x * 256)
        atomicAdd(&h[dst[i] >> BSH], 1);
    __syncthreads();
    for (int i = threadIdx.x; i < nbuk; i += 256)
        if (h[i]) atomicAdd(&bcnt[i], h[i]);
}

// single block: exclusive scan of bcnt -> bstart (+cursorA copy); nbuk <= 1024
__global__ void bucket_scan_k(const int* __restrict__ bcnt, int nbuk, int ne,
                              int* __restrict__ bstart, int* __restrict__ cursorA) {
    __shared__ int psum[256];
    int tid = threadIdx.x;
    int v[4], s = 0;
#pragma unroll
    for (int j = 0; j < 4; j++) {
        int idx = tid * 4 + j;
        v[j] = (idx < nbuk) ? bcnt[idx] : 0;
        s += v[j];
    }
    psum[tid] = s;
    __syncthreads();
    for (int o = 1; o < 256; o <<= 1) {
        int t = (tid >= o) ? psum[tid - o] : 0;
        __syncthreads();
        psum[tid] += t;
        __syncthreads();
    }
    int run = psum[tid] - s;
#pragma unroll
    for (int j = 0; j < 4; j++) {
        int idx = tid * 4 + j;
        if (idx < nbuk) { bstart[idx] = run; cursorA[idx] = run; }
        run += v[j];
    }
    if (tid == 0) bstart[nbuk] = ne;
}

// phase A: per-tile LDS histogram -> block-reserve runs -> contiguous-ish int2 writes
__global__ __launch_bounds__(256) void partA_k(const int* __restrict__ src,
                                               const int* __restrict__ dst, int ne,
                                               int* __restrict__ cursorA,
                                               int2* __restrict__ buf, int nbuk) {
    __shared__ int h[1024];
    __shared__ int base[1024];
    int t0 = blockIdx.x * TILEE;
    int tend = t0 + TILEE < ne ? t0 + TILEE : ne;
    for (int i = threadIdx.x; i < nbuk; i += 256) h[i] = 0;
    __syncthreads();
    for (int i = t0 + threadIdx.x; i < tend; i += 256)
        atomicAdd(&h[dst[i] >> BSH], 1);
    __syncthreads();
    for (int i = threadIdx.x; i < nbuk; i += 256) {
        int c = h[i];
        base[i] = c ? atomicAdd(&cursorA[i], c) : 0;
        h[i] = 0;  // reuse as block-local cursor
    }
    __syncthreads();
    for (int i = t0 + threadIdx.x; i < tend; i += 256) {
        int d = dst[i];
        int bkt = d >> BSH;
        int pos = base[bkt] + atomicAdd(&h[bkt], 1);
        buf[pos] = make_int2(src[i], d & (BDST - 1));
    }
}

// phase B: one block per bucket; per-dst count+scan in LDS, write cs into the
// bucket's private contiguous region; also emits rowptr for this bucket.
__global__ __launch_bounds__(256) void partB_k(const int2* __restrict__ buf,
                                               const int* __restrict__ bstart,
                                               int ndst, int ne,
                                               int* __restrict__ cs,
                                               int* __restrict__ rowptr) {
    __shared__ int off[BDST];
    __shared__ int cur[BDST];
    __shared__ int psum[256];
    int b = blockIdx.x;
    int tid = threadIdx.x;
    int lo = bstart[b], hi = bstart[b + 1];
    for (int d = tid; d < BDST; d += 256) { off[d] = 0; cur[d] = 0; }
    __syncthreads();
    for (int i = lo + tid; i < hi; i += 256)
        atomicAdd(&off[buf[i].y], 1);
    __syncthreads();
    int base_d = tid * 8;
    int loc[8], s = 0;
#pragma unroll
    for (int j = 0; j < 8; j++) { loc[j] = off[base_d + j]; s += loc[j]; }
    psum[tid] = s;
    __syncthreads();
    for (int o = 1; o < 256; o <<= 1) {
        int t = (tid >= o) ? psum[tid - o] : 0;
        __syncthreads();
        psum[tid] += t;
        __syncthreads();
    }
    int run = psum[tid] - s;
#pragma unroll
    for (int j = 0; j < 8; j++) { int c = loc[j]; off[base_d + j] = run; run += c; }
    __syncthreads();
    int dbase = b << BSH;
    for (int d = tid; d < BDST; d += 256) {
        int gd = dbase + d;
        if (gd < ndst) rowptr[gd] = lo + off[d];
    }
    if (b == 0 && tid == 0) rowptr[ndst] = ne;
    for (int i = lo + tid; i < hi; i += 256) {
        int2 p = buf[i];
        int pos = lo + off[p.y] + atomicAdd(&cur[p.y], 1);
        cs[pos] = p.x;
    }
}

// ---------------- pull SPMM, float4 / 8-edge-parallel ----------------
// one wave per dst row: edge slot = lane>>3 (8 parallel edges => 8 lines/instr),
// feature quad = (lane&7)*4; butterfly-reduce over edge slots.
__global__ __launch_bounds__(256) void spmm_pull_k(const float* __restrict__ z,
                                                   const int* __restrict__ idx,
                                                   const int* __restrict__ rowptr,
                                                   float* __restrict__ out, int n) {
    int wave = (blockIdx.x * 256 + threadIdx.x) >> 6;
    if (wave >= n) return;
    int lane = threadIdx.x & 63;
    int fg = (lane & 7) * 4;
    int es = lane >> 3;
    int b = rowptr[wave], e = rowptr[wave + 1];
    float4 acc = make_float4(0.f, 0.f, 0.f, 0.f);
    for (int i = b + es; i < e; i += 8) {
        float4 v = *(const float4*)(z + (size_t)idx[i] * F + fg);
        acc.x += v.x; acc.y += v.y; acc.z += v.z; acc.w += v.w;
    }
#pragma unroll
    for (int s = 8; s < 64; s <<= 1) {
        acc.x += __shfl_xor(acc.x, s);
        acc.y += __shfl_xor(acc.y, s);
        acc.z += __shfl_xor(acc.z, s);
        acc.w += __shfl_xor(acc.w, s);
    }
    if (es == 0) *(float4*)(out + (size_t)wave * F + fg) = acc;
}

// ---------------- main linear, 32 rows/block ----------------
// R4: latency-bound at Occupancy 11% (VGPR=180 -> 2 waves/SIMD). Cap regs with
// __launch_bounds__(256,4) (<=128 VGPR -> 4 blocks/CU; LDS 26KB allows 6) and
// limit k-loop unroll to 4 so the natural live set fits without spilling.
// Gathers (auxidx -> auxsrc row) hoisted to the very top so their ~400-900cy
// latency overlaps the Wint staging loads.
__global__ __launch_bounds__(256, 4) void main_linear_k(
    const float* __restrict__ in0, const float* __restrict__ deg,
    const float* __restrict__ aux32, const float* __restrict__ auxsrc,
    const int* __restrict__ auxidx,
    const float* __restrict__ Wint_g, const float* __restrict__ bt,
    float* __restrict__ acc, int R)
{
    __shared__ float Wint[4096];
    __shared__ float srow_t[32 * 36];
    __shared__ float arow_t[32 * 36];
    __shared__ float sdeg[32];

    int tid = threadIdx.x;
    int base = blockIdx.x * 32;
    int r = tid >> 3;
    int c = (tid & 7) * 4;
    int row = base + r;

    // issue the dependent gather chain first
    int arow = row;
    if (!aux32 && row < R) arow = auxidx[row];
    float4 sv = make_float4(0.f, 0.f, 0.f, 0.f);
    float4 av = make_float4(0.f, 0.f, 0.f, 0.f);
    if (row < R) {
        sv = *(const float4*)(in0 + (size_t)row * F + c);
        if (aux32) av = *(const float4*)(aux32 + (size_t)row * F + c);
        else       av = *(const float4*)(auxsrc + (size_t)arow * F + c);
    }
    {
        const float4* g4 = (const float4*)Wint_g;
        float4* s4 = (float4*)Wint;
#pragma unroll
        for (int i = 0; i < 4; i++) s4[tid + i * 256] = g4[tid + i * 256];
    }
    srow_t[(c + 0) * 36 + r] = sv.x;
    srow_t[(c + 1) * 36 + r] = sv.y;
    srow_t[(c + 2) * 36 + r] = sv.z;
    srow_t[(c + 3) * 36 + r] = sv.w;
    arow_t[(c + 0) * 36 + r] = av.x;
    arow_t[(c + 1) * 36 + r] = av.y;
    arow_t[(c + 2) * 36 + r] = av.z;
    arow_t[(c + 3) * 36 + r] = av.w;
    if (tid < 32) sdeg[tid] = (base + tid < R) ? deg[base + tid] : 0.f;
    __syncthreads();

    int f = tid & 31, lr = tid >> 5;
    int r0 = lr * 4;
    float a0[4] = {0.f, 0.f, 0.f, 0.f};
    float a1[4] = {0.f, 0.f, 0.f, 0.f};
    float a2[4] = {0.f, 0.f, 0.f, 0.f};
    const float4* W4 = (const float4*)Wint;
#pragma unroll 4
    for (int k = 0; k < 32; k++) {
        float4 w = W4[k * 32 + f];
        float4 s = *(const float4*)(srow_t + k * 36 + r0);
        float4 a = *(const float4*)(arow_t + k * 36 + r0);
        a0[0] = fmaf(s.x, w.x, a0[0]); a1[0] = fmaf(s.x, w.y, a1[0]); a2[0] = fmaf(a.x, w.z, a2[0]);
        a0[1] = fmaf(s.y, w.x, a0[1]); a1[1] = fmaf(s.y, w.y, a1[1]); a2[1] = fmaf(a.y, w.z, a2[1]);
        a0[2] = fmaf(s.z, w.x, a0[2]); a1[2] = fmaf(s.z, w.y, a1[2]); a2[2] = fmaf(a.z, w.z, a2[2]);
        a0[3] = fmaf(s.w, w.x, a0[3]); a1[3] = fmaf(s.w, w.y, a1[3]); a2[3] = fmaf(a.w, w.z, a2[3]);
    }
    float btf = bt[f];
#pragma unroll
    for (int j = 0; j < 4; j++) {
        int rr = base + r0 + j;
        if (rr < R) acc[(size_t)rr * F + f] = a0[j] + sdeg[r0 + j] * a1[j] + a2[j] + btf;
    }
}

// ---------------- acc += z @ W^T ----------------
// Same occupancy treatment as main_linear_k (identical structure).
__global__ __launch_bounds__(256, 4) void accum_linear_k(const float* __restrict__ z,
                                                         const float* __restrict__ Wl,
                                                         float* __restrict__ acc, int R) {
    __shared__ float Wt[1024];
    __shared__ float zt[32 * 36];
    int tid = threadIdx.x;
    int base = blockIdx.x * 32;
    int r = tid >> 3;
    int c = (tid & 7) * 4;
    int row = base + r;
    float4 v = make_float4(0.f, 0.f, 0.f, 0.f);
    if (row < R) v = *(const float4*)(z + (size_t)row * F + c);
    ((float4*)Wt)[tid] = ((const float4*)Wl)[tid];
    zt[(c + 0) * 36 + r] = v.x;
    zt[(c + 1) * 36 + r] = v.y;
    zt[(c + 2) * 36 + r] = v.z;
    zt[(c + 3) * 36 + r] = v.w;
    __syncthreads();

    int f = tid & 31, lr = tid >> 5;
    int r0 = lr * 4;
    float a[4] = {0.f, 0.f, 0.f, 0.f};
#pragma unroll 4
    for (int k = 0; k < 32; k++) {
        float w = Wt[k * 32 + f];
        float4 s = *(const float4*)(zt + k * 36 + r0);
        a[0] = fmaf(s.x, w, a[0]);
        a[1] = fmaf(s.y, w, a[1]);
        a[2] = fmaf(s.z, w, a[2]);
        a[3] = fmaf(s.w, w, a[3]);
    }
#pragma unroll
    for (int j = 0; j < 4; j++) {
        int rr = base + r0 + j;
        if (rr < R) acc[(size_t)rr * F + f] += a[j];
    }
}

// ---------------- half-ReLU + per-column stats ----------------
__global__ __launch_bounds__(256) void stats_relu_k(float* __restrict__ acc, int R,
                                                    float* __restrict__ stats) {
    int total = R * F;
    int stride = gridDim.x * 256;
    float s = 0.f, ss = 0.f;
    for (int i = blockIdx.x * 256 + threadIdx.x; i < total; i += stride) {
        float v = acc[i];
        if ((i & 31) >= 16) v = fmaxf(v, 0.f);
        acc[i] = v;
        s += v;
        ss += v * v;
    }
    __shared__ float Ss[256], Sq[256];
    Ss[threadIdx.x] = s; Sq[threadIdx.x] = ss;
    __syncthreads();
    for (int off = 128; off >= 32; off >>= 1) {
        if (threadIdx.x < off) {
            Ss[threadIdx.x] += Ss[threadIdx.x + off];
            Sq[threadIdx.x] += Sq[threadIdx.x + off];
        }
        __syncthreads();
    }
    if (threadIdx.x < 32) {
        atomicAdd(&stats[threadIdx.x], Ss[threadIdx.x]);
        atomicAdd(&stats[32 + threadIdx.x], Sq[threadIdx.x]);
    }
}

__global__ void scalebias_k(const float* __restrict__ stats,
                            const float* __restrict__ sc_x, const float* __restrict__ bi_x,
                            const float* __restrict__ sc_y, const float* __restrict__ bi_y,
                            float* __restrict__ sb, int Rx, int Ry) {
    int tid = threadIdx.x;
    if (tid >= 64) return;
    int side = tid >> 5, f = tid & 31;
    const float* st = stats + side * 64;
    float Rn = side ? (float)Ry : (float)Rx;
    float mean = st[f] / Rn;
    float var = st[32 + f] / Rn - mean * mean;
    float a = rsqrtf(var + BN_EPS) * (side ? sc_y[f] : sc_x[f]);
    float b = (side ? bi_y[f] : bi_x[f]) - mean * a;
    sb[side * 64 + f] = a;
    sb[side * 64 + 32 + f] = b;
}

__global__ __launch_bounds__(256) void finalize_k(const float* __restrict__ acc,
                                                  const float* __restrict__ sb,
                                                  float* __restrict__ out, int R) {
    int i = blockIdx.x * 256 + threadIdx.x;
    if (i >= R * F) return;
    int f = i & 31;
    out[i] = acc[i] * sb[f] + sb[32 + f];
}

extern "C" void kernel_launch(void* const* d_in, const int* in_sizes, int n_in,
                              void* d_out, int out_size, void* d_ws, size_t ws_size,
                              hipStream_t stream) {
    const float* x       = (const float*)d_in[0];
    const float* y       = (const float*)d_in[1];
    const float* deg_g   = (const float*)d_in[2];
    const float* deg_lg  = (const float*)d_in[3];
    const float* th_mw   = (const float*)d_in[4];
    const float* th_mb   = (const float*)d_in[5];
    const float* th_lw   = (const float*)d_in[6];
    const float* th_lb   = (const float*)d_in[7];
    const float* ga_mw   = (const float*)d_in[8];
    const float* ga_mb   = (const float*)d_in[9];
    const float* ga_lw   = (const float*)d_in[10];
    const float* ga_lb   = (const float*)d_in[11];
    const float* bn_x_sc = (const float*)d_in[12];
    const float* bn_x_bi = (const float*)d_in[13];
    const float* bn_y_sc = (const float*)d_in[14];
    const float* bn_y_bi = (const float*)d_in[15];
    const int*   g_src   = (const int*)d_in[16];
    const int*   g_dst   = (const int*)d_in[17];
    const int*   lg_src  = (const int*)d_in[18];
    const int*   lg_dst  = (const int*)d_in[19];
    const int*   pm_pd   = (const int*)d_in[20];
    float* out = (float*)d_out;

    const int N  = in_sizes[0] / F;
    const int E  = in_sizes[1] / F;
    const int LE = in_sizes[18];
    const int nbuk = (E + BDST - 1) >> BSH;

    // ---- workspace ----
    float* ws    = (float*)d_ws;
    float* stats = ws;                 // 128
    float* sb    = ws + 128;           // 128
    float* Wp    = ws + 256;           // 14400
    float* zA_x  = ws + 256 + 14400;
    float* zB_x  = zA_x + (size_t)N * F;
    float* acc_x = zB_x + (size_t)N * F;
    float* pmpd  = acc_x + (size_t)N * F;
    float* zA_y  = pmpd + (size_t)N * F;
    float* zB_y  = zA_y + (size_t)E * F;
    float* acc_y = zB_y + (size_t)E * F;
    int* ip        = (int*)(acc_y + (size_t)E * F);
    int* rowptr_g  = ip;                    // N+1
    int* counts_g  = rowptr_g + (N + 1);    // N
    int* cs_g      = counts_g + N;          // E
    int* ce_g      = cs_g + E;              // E
    int* rowptr_lg = ce_g + E;              // E+1
    int* cs_lg     = rowptr_lg + (E + 1);   // LE
    int* bcnt      = cs_lg + LE;            // 1024
    int* bstart    = bcnt + 1024;           // 1025
    int* cursorA   = bstart + 1025;         // 1024
    int* bsums_g   = cursorA + 1024;        // 256
    int2* buf      = (int2*)zB_y;           // LE int2 (aliased; free until h2-y pull)

    const float* WintX = Wp;
    const float* WlX   = Wp + 4096;
    const float* btX   = Wp + 7168;
    const float* WintY = Wp + 7200;
    const float* WlY   = Wp + 11296;
    const float* btY   = Wp + 14368;

    const int nrx = (N + 31) / 32;
    const int nry = (E + 31) / 32;
    const int pull_gx = (N + 3) / 4;   // 4 waves/block, 1 row/wave
    const int pull_gy = (E + 3) / 4;
    const int nbs_g = (N + SCAN_CHUNK - 1) / SCAN_CHUNK;

    prep_k<<<16, 256, 0, stream>>>(th_mw, th_mb, th_lw, th_lb,
                                   ga_mw, ga_mb, ga_lw, ga_lb, Wp);
    hipMemsetAsync(stats, 0, 128 * sizeof(float), stream);
    hipMemsetAsync(counts_g, 0, (size_t)N * sizeof(int), stream);
    hipMemsetAsync(bcnt, 0, 1024 * sizeof(int), stream);

    // ---- CSR build: g (atomic path) ----
    hist_k<<<(E + 255) / 256, 256, 0, stream>>>(g_dst, E, counts_g);
    scan_block_k<<<nbs_g, 256, 0, stream>>>(counts_g, N, rowptr_g, bsums_g);
    scan_bsums_k<<<1, 256, 0, stream>>>(bsums_g, nbs_g);
    scan_add_k<<<(N + 255) / 256, 256, 0, stream>>>(rowptr_g, N, E, bsums_g);
    hipMemcpyAsync(counts_g, rowptr_g, (size_t)N * sizeof(int),
                   hipMemcpyDeviceToDevice, stream);
    scatter_g_k<<<(E + 255) / 256, 256, 0, stream>>>(g_src, g_dst, E,
                                                     counts_g, cs_g, ce_g);

    // ---- CSR build: lg (partitioned) ----
    bucket_hist_k<<<1024, 256, 0, stream>>>(lg_dst, LE, bcnt, nbuk);
    bucket_scan_k<<<1, 256, 0, stream>>>(bcnt, nbuk, LE, bstart, cursorA);
    partA_k<<<(LE + TILEE - 1) / TILEE, 256, 0, stream>>>(lg_src, lg_dst, LE,
                                                          cursorA, buf, nbuk);
    partB_k<<<nbuk, 256, 0, stream>>>(buf, bstart, E, LE, cs_lg, rowptr_lg);

    // ---------- x side ----------
    spmm_pull_k<<<pull_gx, 256, 0, stream>>>(y, ce_g, rowptr_g, pmpd, N);      // pmpd_y
    main_linear_k<<<nrx, 256, 0, stream>>>(x, deg_g, pmpd, nullptr, nullptr,
                                           WintX, btX, acc_x, N);
    spmm_pull_k<<<pull_gx, 256, 0, stream>>>(x, cs_g, rowptr_g, zA_x, N);      // h1
    accum_linear_k<<<nrx, 256, 0, stream>>>(zA_x, WlX, acc_x, N);
    spmm_pull_k<<<pull_gx, 256, 0, stream>>>(zA_x, cs_g, rowptr_g, zB_x, N);   // h2
    accum_linear_k<<<nrx, 256, 0, stream>>>(zB_x, WlX + 1024, acc_x, N);
    spmm_pull_k<<<pull_gx, 256, 0, stream>>>(zB_x, cs_g, rowptr_g, zA_x, N);   // h3
    spmm_pull_k<<<pull_gx, 256, 0, stream>>>(zA_x, cs_g, rowptr_g, zB_x, N);   // h4
    accum_linear_k<<<nrx, 256, 0, stream>>>(zB_x, WlX + 2048, acc_x, N);
    stats_relu_k<<<512, 256, 0, stream>>>(acc_x, N, stats);

    // ---------- y side ----------
    main_linear_k<<<nry, 256, 0, stream>>>(y, deg_lg, nullptr, x, pm_pd,
                                           WintY, btY, acc_y, E);
    spmm_pull_k<<<pull_gy, 256, 0, stream>>>(y, cs_lg, rowptr_lg, zA_y, E);    // h1
    accum_linear_k<<<nry, 256, 0, stream>>>(zA_y, WlY, acc_y, E);
    spmm_pull_k<<<pull_gy, 256, 0, stream>>>(zA_y, cs_lg, rowptr_lg, zB_y, E); // h2 (buf dead now)
    accum_linear_k<<<nry, 256, 0, stream>>>(zB_y, WlY + 1024, acc_y, E);
    spmm_pull_k<<<pull_gy, 256, 0, stream>>>(zB_y, cs_lg, rowptr_lg, zA_y, E); // h3
    spmm_pull_k<<<pull_gy, 256, 0, stream>>>(zA_y, cs_lg, rowptr_lg, zB_y, E); // h4
    accum_linear_k<<<nry, 256, 0, stream>>>(zB_y, WlY + 2048, acc_y, E);
    stats_relu_k<<<1024, 256, 0, stream>>>(acc_y, E, stats + 64);

    // ---------- BN fold + write ----------
    scalebias_k<<<1, 64, 0, stream>>>(stats, bn_x_sc, bn_x_bi, bn_y_sc, bn_y_bi,
                                      sb, N, E);
    finalize_k<<<(N * F + 255) / 256, 256, 0, stream>>>(acc_x, sb, out, N);
    finalize_k<<<(E * F + 255) / 256, 256, 0, stream>>>(acc_y, sb + 64,
                                                        out + (size_t)N * F, E);
}